// Round 1
// baseline (56.604 us; speedup 1.0000x reference)
//
#include <hip/hip_runtime.h>
#include <hip/hip_bf16.h>

#define N_CELLS 776
#define N_ANCHORS 3
#define N_CH 7
#define CONF_THRESH 0.8f
#define NO_OBJECT 0.5f

// One block, one thread per cell. 776 cells -> 1024-thread block (16 waves).
// Data is tiny (65 KB); kernel is launch-overhead bound, so minimize to a
// single launch with an in-block reduction and a direct scalar store.
__global__ __launch_bounds__(1024) void yolo_loss_kernel(
    const float* __restrict__ pred,   // (N_CELLS*N_ANCHORS, N_CH) row-major
    const float* __restrict__ label,  // (N_CH,)
    float* __restrict__ out)          // scalar
{
    const int tid = threadIdx.x;

    // Label broadcast: uniform address -> compiler emits scalar loads.
    const float l0 = label[0], l1 = label[1], l2 = label[2], l3 = label[3];
    const float l4 = label[4], l5 = label[5], l6 = label[6];

    float loss = 0.0f;
    if (tid < N_CELLS) {
        const float* row = pred + tid * (N_ANCHORS * N_CH);

        // argmax over anchors with first-occurrence tie semantics:
        // strict '>' against running best, iterating a = 0..2.
        float best_iou = -INFINITY;
        float b[N_CH];
        #pragma unroll
        for (int a = 0; a < N_ANCHORS; ++a) {
            const float* p = row + a * N_CH;
            const float px = p[0], py = p[1], pw = p[2], ph = p[3];
            const float ax = fmaxf(px - pw * 0.5f, l0 - l2 * 0.5f);
            const float ay = fmaxf(py - ph * 0.5f, l1 - l3 * 0.5f);
            const float bx = fminf(px + pw * 0.5f, l0 + l2 * 0.5f);
            const float by = fminf(py + ph * 0.5f, l1 + l3 * 0.5f);
            const float inter = fabsf(fmaxf(bx - ax, 0.0f) * fmaxf(by - ay, 0.0f));
            const float area_a = fabsf(pw * ph);
            const float area_b = fabsf(l2 * l3);
            const float iou = inter / (area_a + area_b - inter);
            if (iou > best_iou) {
                best_iou = iou;
                #pragma unroll
                for (int c = 0; c < N_CH; ++c) b[c] = p[c];
            }
        }

        // Loss, replicating the reference exactly (note: wh_loss reuses
        // label[0]/label[1] and best[:,0]/best[:,1] — that's the reference's
        // own behavior, keep it).
        const float dx = l0 - b[0];
        const float dy = l1 - b[1];
        const float xy_loss = dx * dx + dy * dy;
        const float sw0 = sqrtf(l0) - sqrtf(b[0]);
        const float sw1 = sqrtf(l1) - sqrtf(b[1]);
        const float wh_loss = sw0 * sw0 + sw1 * sw1;
        const float coord_loss = xy_loss + wh_loss;

        const bool has_obj = b[4] > CONF_THRESH;
        const float d5 = l5 - b[5];
        const float d6 = l6 - b[6];
        const float class_loss = has_obj ? (d5 * d5 + d6 * d6) : 0.0f;
        const float d4 = l4 - b[4];
        const float conf_sq = d4 * d4;
        const float conf_loss = has_obj ? conf_sq : NO_OBJECT * conf_sq;

        loss = coord_loss + class_loss + conf_loss;
    }

    // Block reduction: wave64 shuffle, then LDS across 16 waves.
    #pragma unroll
    for (int off = 32; off > 0; off >>= 1)
        loss += __shfl_down(loss, off, 64);

    __shared__ float smem[16];
    const int wave = tid >> 6;
    if ((tid & 63) == 0) smem[wave] = loss;
    __syncthreads();

    if (tid == 0) {
        float tot = 0.0f;
        #pragma unroll
        for (int w = 0; w < 16; ++w) tot += smem[w];
        out[0] = tot;
    }
}

extern "C" void kernel_launch(void* const* d_in, const int* in_sizes, int n_in,
                              void* d_out, int out_size, void* d_ws, size_t ws_size,
                              hipStream_t stream) {
    const float* pred  = (const float*)d_in[0];   // (2328, 7) fp32
    const float* label = (const float*)d_in[1];   // (7,) fp32
    float* out = (float*)d_out;                   // scalar fp32
    yolo_loss_kernel<<<1, 1024, 0, stream>>>(pred, label, out);
}